// Round 9
// baseline (115.842 us; speedup 1.0000x reference)
//
#include <hip/hip_runtime.h>
#include <math.h>

#define BATCH 4
#define NPTS 4096
#define DF 64
#define ROWB 128               // bytes per point row in bf16
#define RW 64                  // rows per wave
#define CW 512                 // cols (chunk) per wave
#define CTILE 16               // cols per inner iteration
#define NITER (CW / CTILE)     // 32
#define NCS (NPTS / CW)        // 8 col chunks
#define INV_T 100.0f
#define MARGIN 0.16f           // skipped weights < exp(-16) ~ 1.1e-7
#define HM2C (0.5f * MARGIN * MARGIN)
#define SCALE (1.0f / 16384.0f)

typedef float  f32x4 __attribute__((ext_vector_type(4)));
typedef short  s16x8 __attribute__((ext_vector_type(8)));
typedef unsigned short u16;

// ws layout (~7.25 MB)
#define SZ_B   (BATCH * NPTS * DF * 2)   // bf16 array: 2 MB
#define SZ_N   (BATCH * NPTS * 4)        // norm array: 64 KB
#define OFF_XB 0
#define OFF_YB (OFF_XB + SZ_B)
#define OFF_X2 (OFF_YB + SZ_B)
#define OFF_Y2 (OFF_X2 + SZ_N)
#define OFF_PART (OFF_Y2 + SZ_N)         // [dirb][NCS][NPTS][3] floats: 3 MB

__device__ __forceinline__ u16 f2bf(float f) {
    unsigned u = __float_as_uint(f);
    unsigned r = (u + 0x7fffu + ((u >> 16) & 1u)) >> 16;   // RNE
    return (u16)r;
}

// fp32 -> bf16 (XOR-swizzled row layout: byte ^= (point&7)<<4) + fp32 norms.
// Pre-swizzling in global lets fragment loads read bank/channel-friendly
// 16B blocks directly from L2 with the same offset formula everywhere.
__global__ __launch_bounds__(256) void prep_kernel(const float* __restrict__ X,
                                                   const float* __restrict__ Y,
                                                   u16* __restrict__ xb, u16* __restrict__ yb,
                                                   float* __restrict__ x2, float* __restrict__ y2,
                                                   float* __restrict__ out) {
    if (blockIdx.x == 0 && blockIdx.y == 0 && threadIdx.x == 0) out[0] = 0.0f;
    const float* src = blockIdx.y ? Y : X;
    u16* dstb   = blockIdx.y ? yb : xb;
    float* dstn = blockIdx.y ? y2 : x2;
    int g = blockIdx.x * 256 + threadIdx.x;
    int p = g >> 4;                       // point 0..16383
    int sub = g & 15;                     // 8B chunk within row
    float4 v = ((const float4*)src)[(size_t)p * 16 + sub];
    float n4 = v.x * v.x + v.y * v.y + v.z * v.z + v.w * v.w;
    #pragma unroll
    for (int m = 1; m < 16; m <<= 1) n4 += __shfl_xor(n4, m, 16);
    ushort4 hh;
    hh.x = f2bf(v.x); hh.y = f2bf(v.y); hh.z = f2bf(v.z); hh.w = f2bf(v.w);
    int byteoff = (sub << 3) ^ ((p & 7) << 4);   // swizzle (XOR bits 4..6)
    *(ushort4*)((char*)dstb + (size_t)p * ROWB + byteoff) = hh;
    if (sub == 0) dstn[p] = n4;
}

// Barrier-free two-phase softmin. One WAVE owns 64 rows x 512 cols of one
// (b, dir): A-frags persistent in registers, B-frags streamed directly from
// the pre-swizzled global array (L2-resident, ~1MB/XCD after swizzle).
// No LDS, no __syncthreads => pipes overlap freely across 16 waves/CU.
__global__ __launch_bounds__(256, 4) void softmin_wave(const u16* __restrict__ xb,
                                                       const u16* __restrict__ yb,
                                                       const float* __restrict__ x2g,
                                                       const float* __restrict__ y2g,
                                                       float* __restrict__ part) {
    const int tid = threadIdx.x;
    // XCD-chunked bijective swizzle (1024 blocks = 8 XCDs x 128): each XCD
    // handles exactly one (dir,b) => per-XCD L2 working set ~1MB.
    const int bid = blockIdx.x;
    const int swzbid = (bid & 7) * 128 + (bid >> 3);
    const int dirb = swzbid >> 7;             // 0..7 = dir*4 + b
    const int lin = (swzbid & 127) * 4 + (tid >> 6);   // 0..511
    const int cs   = lin & 7;
    const int rowT = lin >> 3;                // 0..63
    const int b    = dirb & 3;
    const int dir  = dirb >> 2;

    const int h = (tid >> 4) & 3;        // k-octet / D-row group
    const int c = tid & 15;              // fragment lane slot

    const u16 *rowsrc, *colsrc; const float *rn, *cn;
    if (dir == 0) { rowsrc = xb; colsrc = yb; rn = x2g; cn = y2g; }
    else          { rowsrc = yb; colsrc = xb; rn = y2g; cn = x2g; }

    const size_t bpts = (size_t)b * NPTS;
    const u16* rbase = rowsrc + (bpts + (size_t)rowT * RW) * DF;
    const char* cbase = (const char*)(colsrc + (bpts + (size_t)cs * CW) * DF);
    const float* cyp = cn + bpts + (size_t)cs * CW + c;
    const float* rnb = rn + bpts + (size_t)rowT * RW;

    // A fragments (persistent): rows st*16 + c, pre-swizzled offsets
    s16x8 af[4][2];
    #pragma unroll
    for (int st = 0; st < 4; ++st) {
        int rr = st * 16 + c;
        #pragma unroll
        for (int kp = 0; kp < 2; ++kp) {
            int o = (h * 16 + kp * 64) ^ ((rr & 7) << 4);
            af[st][kp] = *(const s16x8*)((const char*)rbase + rr * ROWB + o);
        }
    }
    // B fragment byte-offsets within a 16-col tile (col = c)
    int bo0 = c * ROWB + ((h * 16) ^ ((c & 7) << 4));
    int bo1 = c * ROWB + ((h * 16 + 64) ^ ((c & 7) << 4));

    // ================= PASS 1: exact chunk max of u = x.y - y2/2 =================
    float mx[4][4];
    #pragma unroll
    for (int st = 0; st < 4; ++st)
        #pragma unroll
        for (int r = 0; r < 4; ++r) mx[st][r] = -INFINITY;

    {
        const char* cb = cbase;
        #pragma unroll 2
        for (int it = 0; it < NITER; ++it) {
            s16x8 b0 = *(const s16x8*)(cb + bo0);
            s16x8 b1 = *(const s16x8*)(cb + bo1);
            float cy = cyp[it * CTILE];
            #pragma unroll
            for (int st = 0; st < 4; ++st) {
                f32x4 a = {0.f, 0.f, 0.f, 0.f};
                a = __builtin_amdgcn_mfma_f32_16x16x32_bf16(af[st][0], b0, a, 0, 0, 0);
                a = __builtin_amdgcn_mfma_f32_16x16x32_bf16(af[st][1], b1, a, 0, 0, 0);
                #pragma unroll
                for (int r = 0; r < 4; ++r)
                    mx[st][r] = fmaxf(mx[st][r], fmaf(-0.5f, cy, a[r]));
            }
            cb += CTILE * ROWB;
        }
    }

    // butterfly max across the 16 col-lanes; derive min distance + gate
    float mval[4][4], gthr[4][4], ssum[4][4], tsum[4][4];
    #pragma unroll
    for (int st = 0; st < 4; ++st) {
        f32x4 xv = *(const f32x4*)(rnb + st * 16 + 4 * h);   // row norms
        #pragma unroll
        for (int r = 0; r < 4; ++r) {
            #pragma unroll
            for (int m = 1; m < 16; m <<= 1)
                mx[st][r] = fmaxf(mx[st][r], __shfl_xor(mx[st][r], m, 16));
            float d2m = fmaf(-2.f, mx[st][r], xv[r]);        // exact min d^2
            mval[st][r] = sqrtf(fmaxf(d2m, 0.f));
            gthr[st][r] = mx[st][r] - MARGIN * mval[st][r] - HM2C;
            ssum[st][r] = 0.f; tsum[st][r] = 0.f;
        }
    }

    // ================= PASS 2: gated weighted sums =================
    {
        const char* cb = cbase;
        #pragma unroll 2
        for (int it = 0; it < NITER; ++it) {
            s16x8 b0 = *(const s16x8*)(cb + bo0);
            s16x8 b1 = *(const s16x8*)(cb + bo1);
            float cy = cyp[it * CTILE];
            #pragma unroll
            for (int st = 0; st < 4; ++st) {
                f32x4 a = {0.f, 0.f, 0.f, 0.f};
                a = __builtin_amdgcn_mfma_f32_16x16x32_bf16(af[st][0], b0, a, 0, 0, 0);
                a = __builtin_amdgcn_mfma_f32_16x16x32_bf16(af[st][1], b1, a, 0, 0, 0);
                #pragma unroll
                for (int r = 0; r < 4; ++r) {
                    float u = fmaf(-0.5f, cy, a[r]);
                    if (__any(u > gthr[st][r])) {   // 4-row x 16-col slice
                        // rebuild mx, d2 = mval^2 + 2*(mx - u)  (no x2 reg)
                        float mxv = fmaf(MARGIN, mval[st][r], gthr[st][r]) + HM2C;
                        float d2 = fmaf(2.f, mxv - u, mval[st][r] * mval[st][r]);
                        float d = sqrtf(fmaxf(d2, 0.f));
                        float e = __expf(INV_T * (mval[st][r] - d));  // ->0 if far
                        ssum[st][r] += e;
                        tsum[st][r] = fmaf(e, d, tsum[st][r]);
                    }
                }
            }
            cb += CTILE * ROWB;
        }
    }

    // butterfly sums across 16 col-lanes; write partial state (3 floats)
    #pragma unroll
    for (int st = 0; st < 4; ++st)
        #pragma unroll
        for (int r = 0; r < 4; ++r)
            #pragma unroll
            for (int m = 1; m < 16; m <<= 1) {
                ssum[st][r] += __shfl_xor(ssum[st][r], m, 16);
                tsum[st][r] += __shfl_xor(tsum[st][r], m, 16);
            }
    if (c == 0) {
        #pragma unroll
        for (int st = 0; st < 4; ++st)
            #pragma unroll
            for (int r = 0; r < 4; ++r) {
                int row = rowT * RW + st * 16 + 4 * h + r;
                size_t idx = (((size_t)dirb * NCS + cs) * NPTS + row) * 3;
                part[idx + 0] = mval[st][r];
                part[idx + 1] = ssum[st][r];
                part[idx + 2] = tsum[st][r];
            }
    }
}

// Merge NCS partial states per row, cube, reduce, atomicAdd into out[0].
__global__ __launch_bounds__(256) void merge_kernel(const float* __restrict__ part,
                                                    float* __restrict__ out) {
    __shared__ float red[4];
    int g = blockIdx.x * 256 + threadIdx.x;   // dirb*4096 + row
    int dirb = g >> 12;
    int row  = g & 4095;
    float nm = INFINITY;
    float mnv[NCS], sv[NCS], tv[NCS];
    #pragma unroll
    for (int k = 0; k < NCS; ++k) {
        const float* p = part + (((size_t)dirb * NCS + k) * NPTS + row) * 3;
        mnv[k] = p[0]; sv[k] = p[1]; tv[k] = p[2];
        nm = fminf(nm, mnv[k]);
    }
    float S = 0.f, T = 0.f;
    #pragma unroll
    for (int k = 0; k < NCS; ++k) {
        float cw = __expf(INV_T * (nm - mnv[k]));
        S += sv[k] * cw;
        T += tv[k] * cw;
    }
    float sm = T / S;
    float v = sm * sm * sm * SCALE;
    #pragma unroll
    for (int m = 1; m < 64; m <<= 1) v += __shfl_xor(v, m, 64);
    if ((threadIdx.x & 63) == 0) red[threadIdx.x >> 6] = v;
    __syncthreads();
    if (threadIdx.x == 0) atomicAdd(out, red[0] + red[1] + red[2] + red[3]);
}

extern "C" void kernel_launch(void* const* d_in, const int* in_sizes, int n_in,
                              void* d_out, int out_size, void* d_ws, size_t ws_size,
                              hipStream_t stream) {
    const float* x = (const float*)d_in[0];
    const float* y = (const float*)d_in[1];
    float* out = (float*)d_out;
    char* ws = (char*)d_ws;

    u16* xb = (u16*)(ws + OFF_XB);
    u16* yb = (u16*)(ws + OFF_YB);
    float* x2 = (float*)(ws + OFF_X2);
    float* y2 = (float*)(ws + OFF_Y2);
    float* part = (float*)(ws + OFF_PART);

    prep_kernel<<<dim3(1024, 2), 256, 0, stream>>>(x, y, xb, yb, x2, y2, out);
    softmin_wave<<<1024, 256, 0, stream>>>(xb, yb, x2, y2, part);
    merge_kernel<<<128, 256, 0, stream>>>(part, out);
}

// Round 10
// 86.609 us; speedup vs baseline: 1.3375x; 1.3375x over previous
//
#include <hip/hip_runtime.h>
#include <math.h>

#define BATCH 4
#define NPTS 4096
#define DF 64
#define ROWB 128               // bytes per point row in bf16
#define RW 32                  // rows per wave (st = 2) -- keeps state under 64 VGPR
#define CW 512                 // cols (chunk) per wave
#define CTILE 16               // cols per inner iteration
#define NITER (CW / CTILE)     // 32
#define NCS (NPTS / CW)        // 8 col chunks
#define NRT (NPTS / RW)        // 128 row tiles
#define INV_T 100.0f
#define MARGIN 0.16f           // skipped weights < exp(-16) ~ 1.1e-7
#define HM2C (0.5f * MARGIN * MARGIN)
#define SCALE (1.0f / 16384.0f)

typedef float  f32x4 __attribute__((ext_vector_type(4)));
typedef short  s16x8 __attribute__((ext_vector_type(8)));
typedef unsigned short u16;

// ws layout (~7.25 MB)
#define SZ_B   (BATCH * NPTS * DF * 2)   // bf16 array: 2 MB
#define SZ_N   (BATCH * NPTS * 4)        // norm array: 64 KB
#define OFF_XB 0
#define OFF_YB (OFF_XB + SZ_B)
#define OFF_X2 (OFF_YB + SZ_B)
#define OFF_Y2 (OFF_X2 + SZ_N)
#define OFF_PART (OFF_Y2 + SZ_N)         // [dirb][NCS][NPTS][3] floats: 3 MB

__device__ __forceinline__ u16 f2bf(float f) {
    unsigned u = __float_as_uint(f);
    unsigned r = (u + 0x7fffu + ((u >> 16) & 1u)) >> 16;   // RNE
    return (u16)r;
}

// fp32 -> bf16 (XOR-swizzled row layout: byte ^= (point&7)<<4) + fp32 norms.
__global__ __launch_bounds__(256) void prep_kernel(const float* __restrict__ X,
                                                   const float* __restrict__ Y,
                                                   u16* __restrict__ xb, u16* __restrict__ yb,
                                                   float* __restrict__ x2, float* __restrict__ y2,
                                                   float* __restrict__ out) {
    if (blockIdx.x == 0 && blockIdx.y == 0 && threadIdx.x == 0) out[0] = 0.0f;
    const float* src = blockIdx.y ? Y : X;
    u16* dstb   = blockIdx.y ? yb : xb;
    float* dstn = blockIdx.y ? y2 : x2;
    int g = blockIdx.x * 256 + threadIdx.x;
    int p = g >> 4;                       // point 0..16383
    int sub = g & 15;                     // 8B chunk within row
    float4 v = ((const float4*)src)[(size_t)p * 16 + sub];
    float n4 = v.x * v.x + v.y * v.y + v.z * v.z + v.w * v.w;
    #pragma unroll
    for (int m = 1; m < 16; m <<= 1) n4 += __shfl_xor(n4, m, 16);
    ushort4 hh;
    hh.x = f2bf(v.x); hh.y = f2bf(v.y); hh.z = f2bf(v.z); hh.w = f2bf(v.w);
    int byteoff = (sub << 3) ^ ((p & 7) << 4);   // swizzle (XOR bits 4..6)
    *(ushort4*)((char*)dstb + (size_t)p * ROWB + byteoff) = hh;
    if (sub == 0) dstn[p] = n4;
}

// Barrier-free two-phase softmin. One WAVE owns 32 rows x 512 cols of one
// (b, dir). A-frags persistent in registers; B-frags streamed directly from
// the pre-swizzled global array (L2-resident per XCD). No LDS, no barriers.
// State registers trimmed to ~60: gthr/ssum/tsum only (mval recomputed as
// d_thr = sqrt(x2 - 2*gthr) in the rare slow path; valid exp reference).
__global__ __launch_bounds__(256, 4) void softmin_wave(const u16* __restrict__ xb,
                                                       const u16* __restrict__ yb,
                                                       const float* __restrict__ x2g,
                                                       const float* __restrict__ y2g,
                                                       float* __restrict__ part) {
    const int tid = threadIdx.x;
    // XCD-bijective swizzle (2048 = 8 XCDs x 256): blocks with bid%8==k land
    // on XCD k and all share dirb=k -> per-XCD L2 working set ~2MB.
    const int bid = blockIdx.x;
    const int swz = (bid & 7) * 256 + (bid >> 3);
    const int dirb = swz >> 8;               // 0..7 = dir*4 + b
    const int rem  = swz & 255;
    const int cs   = rem & 7;                // block-uniform: 4 waves share cols
    const int rtg  = rem >> 3;               // 0..31
    const int w    = tid >> 6;
    const int rowT = rtg * 4 + w;            // 0..127
    const int b    = dirb & 3;
    const int dir  = dirb >> 2;

    const int h = (tid >> 4) & 3;        // k-octet / D-row group
    const int c = tid & 15;              // fragment lane slot

    const u16 *rowsrc, *colsrc; const float *rn, *cn;
    if (dir == 0) { rowsrc = xb; colsrc = yb; rn = x2g; cn = y2g; }
    else          { rowsrc = yb; colsrc = xb; rn = y2g; cn = x2g; }

    const size_t bpts = (size_t)b * NPTS;
    const u16* rbase = rowsrc + (bpts + (size_t)rowT * RW) * DF;
    const char* cbase = (const char*)(colsrc + (bpts + (size_t)cs * CW) * DF);
    const float* cyp = cn + bpts + (size_t)cs * CW + c;
    const float* rnb = rn + bpts + (size_t)rowT * RW;

    // A fragments (persistent): rows st*16 + c, pre-swizzled offsets
    s16x8 af[2][2];
    #pragma unroll
    for (int st = 0; st < 2; ++st) {
        int rr = st * 16 + c;
        #pragma unroll
        for (int kp = 0; kp < 2; ++kp) {
            int o = (h * 16 + kp * 64) ^ ((rr & 7) << 4);
            af[st][kp] = *(const s16x8*)((const char*)rbase + rr * ROWB + o);
        }
    }
    // B fragment byte-offsets within a 16-col tile (col = c)
    const int bo0 = c * ROWB + ((h * 16) ^ ((c & 7) << 4));
    const int bo1 = c * ROWB + ((h * 16 + 64) ^ ((c & 7) << 4));

    // ================= PASS 1: exact chunk max of u = x.y - y2/2 =================
    float mx[2][4];
    #pragma unroll
    for (int st = 0; st < 2; ++st)
        #pragma unroll
        for (int r = 0; r < 4; ++r) mx[st][r] = -INFINITY;

    {
        const char* cb = cbase;
        #pragma unroll 2
        for (int it = 0; it < NITER; ++it) {
            s16x8 b0 = *(const s16x8*)(cb + bo0);
            s16x8 b1 = *(const s16x8*)(cb + bo1);
            float cy = cyp[it * CTILE];
            #pragma unroll
            for (int st = 0; st < 2; ++st) {
                f32x4 a = {0.f, 0.f, 0.f, 0.f};
                a = __builtin_amdgcn_mfma_f32_16x16x32_bf16(af[st][0], b0, a, 0, 0, 0);
                a = __builtin_amdgcn_mfma_f32_16x16x32_bf16(af[st][1], b1, a, 0, 0, 0);
                #pragma unroll
                for (int r = 0; r < 4; ++r)
                    mx[st][r] = fmaxf(mx[st][r], fmaf(-0.5f, cy, a[r]));
            }
            cb += CTILE * ROWB;
        }
    }

    // butterfly max across the 16 col-lanes; gate threshold (mval transient)
    float gthr[2][4], ssum[2][4], tsum[2][4];
    #pragma unroll
    for (int st = 0; st < 2; ++st) {
        f32x4 xv = *(const f32x4*)(rnb + st * 16 + 4 * h);   // row norms
        #pragma unroll
        for (int r = 0; r < 4; ++r) {
            #pragma unroll
            for (int m = 1; m < 16; m <<= 1)
                mx[st][r] = fmaxf(mx[st][r], __shfl_xor(mx[st][r], m, 16));
            float d2m = fmaf(-2.f, mx[st][r], xv[r]);        // exact min d^2
            float mval = sqrtf(fmaxf(d2m, 0.f));
            gthr[st][r] = mx[st][r] - MARGIN * mval - HM2C;  // u>gthr <=> d<mval+M
            ssum[st][r] = 0.f; tsum[st][r] = 0.f;
        }
    }

    // ================= PASS 2: gated weighted sums (ref = d_thr) =================
    {
        const char* cb = cbase;
        #pragma unroll 2
        for (int it = 0; it < NITER; ++it) {
            s16x8 b0 = *(const s16x8*)(cb + bo0);
            s16x8 b1 = *(const s16x8*)(cb + bo1);
            float cy = cyp[it * CTILE];
            #pragma unroll
            for (int st = 0; st < 2; ++st) {
                f32x4 a = {0.f, 0.f, 0.f, 0.f};
                a = __builtin_amdgcn_mfma_f32_16x16x32_bf16(af[st][0], b0, a, 0, 0, 0);
                a = __builtin_amdgcn_mfma_f32_16x16x32_bf16(af[st][1], b1, a, 0, 0, 0);
                #pragma unroll
                for (int r = 0; r < 4; ++r) {
                    float u = fmaf(-0.5f, cy, a[r]);
                    if (__any(u > gthr[st][r])) {   // 4-row x 16-col slice, rare
                        f32x4 xv = *(const f32x4*)(rnb + st * 16 + 4 * h);
                        float d2 = fmaf(-2.f, u, xv[r]);
                        float d = sqrtf(fmaxf(d2, 0.f));
                        float dthr = sqrtf(fmaf(-2.f, gthr[st][r], xv[r])); // = mval+M
                        float e = __expf(INV_T * (dthr - d));  // <= e^16, ->0 if far
                        ssum[st][r] += e;
                        tsum[st][r] = fmaf(e, d, tsum[st][r]);
                    }
                }
            }
            cb += CTILE * ROWB;
        }
    }

    // butterfly sums across 16 col-lanes; write partial state {dthr, s, t}
    #pragma unroll
    for (int st = 0; st < 2; ++st)
        #pragma unroll
        for (int r = 0; r < 4; ++r)
            #pragma unroll
            for (int m = 1; m < 16; m <<= 1) {
                ssum[st][r] += __shfl_xor(ssum[st][r], m, 16);
                tsum[st][r] += __shfl_xor(tsum[st][r], m, 16);
            }
    if (c == 0) {
        #pragma unroll
        for (int st = 0; st < 2; ++st) {
            f32x4 xv = *(const f32x4*)(rnb + st * 16 + 4 * h);
            #pragma unroll
            for (int r = 0; r < 4; ++r) {
                float dthr = sqrtf(fmaf(-2.f, gthr[st][r], xv[r]));
                int row = rowT * RW + st * 16 + 4 * h + r;
                size_t idx = (((size_t)dirb * NCS + cs) * NPTS + row) * 3;
                part[idx + 0] = dthr;
                part[idx + 1] = ssum[st][r];
                part[idx + 2] = tsum[st][r];
            }
        }
    }
}

// Merge NCS partial states per row, cube, reduce, atomicAdd into out[0].
__global__ __launch_bounds__(256) void merge_kernel(const float* __restrict__ part,
                                                    float* __restrict__ out) {
    __shared__ float red[4];
    int g = blockIdx.x * 256 + threadIdx.x;   // dirb*4096 + row
    int dirb = g >> 12;
    int row  = g & 4095;
    float nm = INFINITY;
    float mnv[NCS], sv[NCS], tv[NCS];
    #pragma unroll
    for (int k = 0; k < NCS; ++k) {
        const float* p = part + (((size_t)dirb * NCS + k) * NPTS + row) * 3;
        mnv[k] = p[0]; sv[k] = p[1]; tv[k] = p[2];
        nm = fminf(nm, mnv[k]);
    }
    float S = 0.f, T = 0.f;
    #pragma unroll
    for (int k = 0; k < NCS; ++k) {
        float cw = __expf(INV_T * (nm - mnv[k]));
        S += sv[k] * cw;
        T += tv[k] * cw;
    }
    float sm = T / S;
    float v = sm * sm * sm * SCALE;
    #pragma unroll
    for (int m = 1; m < 64; m <<= 1) v += __shfl_xor(v, m, 64);
    if ((threadIdx.x & 63) == 0) red[threadIdx.x >> 6] = v;
    __syncthreads();
    if (threadIdx.x == 0) atomicAdd(out, red[0] + red[1] + red[2] + red[3]);
}

extern "C" void kernel_launch(void* const* d_in, const int* in_sizes, int n_in,
                              void* d_out, int out_size, void* d_ws, size_t ws_size,
                              hipStream_t stream) {
    const float* x = (const float*)d_in[0];
    const float* y = (const float*)d_in[1];
    float* out = (float*)d_out;
    char* ws = (char*)d_ws;

    u16* xb = (u16*)(ws + OFF_XB);
    u16* yb = (u16*)(ws + OFF_YB);
    float* x2 = (float*)(ws + OFF_X2);
    float* y2 = (float*)(ws + OFF_Y2);
    float* part = (float*)(ws + OFF_PART);

    prep_kernel<<<dim3(1024, 2), 256, 0, stream>>>(x, y, xb, yb, x2, y2, out);
    softmin_wave<<<2048, 256, 0, stream>>>(xb, yb, x2, y2, part);
    merge_kernel<<<128, 256, 0, stream>>>(part, out);
}